// Round 5
// baseline (229.600 us; speedup 1.0000x reference)
//
#include <hip/hip_runtime.h>
#include <hip/hip_bf16.h>

// Problem constants: B=2, C=64, H=64, W=64 -> N=8192 tokens, DH=32.
#define N_TOK   8192
#define DH      32
#define CCH     64
#define HWSZ    4096
#define LOG2E   1.4426950408889634f
#define NCH_O   32     // j-chunks for PV pass: 128 i-tiles x 32 = 4096 waves
#define ITILE   64     // i-rows per wave in PV pass (4 Q fragments)

typedef __attribute__((ext_vector_type(8))) short  bf16x8;
typedef __attribute__((ext_vector_type(4))) short  bf16x4;
typedef __attribute__((ext_vector_type(4))) float  f32x4;

// Bit-pattern f32 -> bf16 short (for MFMA operand vectors / LDS shorts ONLY —
// never assign the result to a __hip_bfloat16: that would value-convert).
static __device__ __forceinline__ short f2bf(float f) {
    __hip_bfloat16 h = __float2bfloat16(f);
    return __builtin_bit_cast(short, h);
}
static __device__ __forceinline__ float bf2f(short s) {
    unsigned u = ((unsigned)(unsigned short)s) << 16;
    return __builtin_bit_cast(float, u);
}

// A/B fragment for mfma_f32_16x16x32_bf16 from row-major [rows][32] bf16:
// lane l supplies row row0+(l&15), k = 8*(l>>4)..+8 (16B load).
static __device__ __forceinline__ bf16x8 load_frag8(const __hip_bfloat16* __restrict__ base,
                                                    int row0, int l) {
    const __hip_bfloat16* p = base + (size_t)(row0 + (l & 15)) * DH + ((l >> 4) << 3);
    return *reinterpret_cast<const bf16x8*>(p);
}

// ---------------------------------------------------------------------------
// K1: q/k/v projections (1024 blocks, 8 tokens each — R3's fast shape).
// Outputs Qb[n][d] (pre-scaled by log2e), Kb[n][d], VTb[d][n] (bf16,
// UNnormalized, transposed via LDS). Block 0 zeroes the zred ticket counters.
// ---------------------------------------------------------------------------
__global__ __launch_bounds__(256) void k_qkv(
        const float* __restrict__ x,
        const float* __restrict__ w1, const float* __restrict__ b1,
        const float* __restrict__ w2, const float* __restrict__ b2,
        const float* __restrict__ w3, const float* __restrict__ b3,
        __hip_bfloat16* __restrict__ Qb, __hip_bfloat16* __restrict__ Kb,
        __hip_bfloat16* __restrict__ VTb, unsigned* __restrict__ cnt) {
    __shared__ float4 w1s[16][32];
    __shared__ float4 w2s[16][32];
    __shared__ float4 w3s[16][32];
    __shared__ short  vt[32][8];      // [d][n_local]
    int t = threadIdx.x;
    if (blockIdx.x == 0 && t < 128) cnt[t] = 0u;
    for (int i = t; i < 512; i += 256) {
        int cg = i >> 5, d = i & 31;
        w1s[cg][d] = *reinterpret_cast<const float4*>(w1 + d * CCH + cg * 4);
        w2s[cg][d] = *reinterpret_cast<const float4*>(w2 + d * CCH + cg * 4);
        w3s[cg][d] = *reinterpret_cast<const float4*>(w3 + d * CCH + cg * 4);
    }
    __syncthreads();
    int d = t & 31, nr = t >> 5;
    int n0 = blockIdx.x * 8;
    int n = n0 + nr;
    int b = n >> 12, hw = n & 4095;
    const float* xp = x + (size_t)b * (CCH * HWSZ) + hw;
    float aq = b1[d], ak = b2[d], av = b3[d];
    #pragma unroll
    for (int cg = 0; cg < 16; ++cg) {
        float x0 = xp[(cg * 4 + 0) * HWSZ];
        float x1 = xp[(cg * 4 + 1) * HWSZ];
        float x2 = xp[(cg * 4 + 2) * HWSZ];
        float x3 = xp[(cg * 4 + 3) * HWSZ];
        float4 a = w1s[cg][d];
        aq = fmaf(a.x, x0, aq); aq = fmaf(a.y, x1, aq);
        aq = fmaf(a.z, x2, aq); aq = fmaf(a.w, x3, aq);
        float4 bb = w2s[cg][d];
        ak = fmaf(bb.x, x0, ak); ak = fmaf(bb.y, x1, ak);
        ak = fmaf(bb.z, x2, ak); ak = fmaf(bb.w, x3, ak);
        float4 cc = w3s[cg][d];
        av = fmaf(cc.x, x0, av); av = fmaf(cc.y, x1, av);
        av = fmaf(cc.z, x2, av); av = fmaf(cc.w, x3, av);
    }
    Qb[(size_t)n * DH + d] = __float2bfloat16(aq * LOG2E);
    Kb[(size_t)n * DH + d] = __float2bfloat16(ak);
    vt[d][nr] = f2bf(av);
    __syncthreads();
    if (t < 32) {   // 32 d-rows x 8 tokens, one 16B chunk per row
        bf16x8 row = *reinterpret_cast<const bf16x8*>(&vt[t][0]);
        *reinterpret_cast<bf16x8*>(VTb + (size_t)t * N_TOK + n0) = row;
    }
}

// ---------------------------------------------------------------------------
// K2 (pass A): Zpart[ic][j] = sum_{i in chunk ic} exp2(q~_i . k_j).
// jt = 64-col j-tile; 16 blocks (64 i-chunks) per jt. The LAST block of each
// jt (ticket counter) reduces the 64 partials in fixed ic order and writes
// rZ[j] = rcp(Z[j]). Deterministic; only 16 uncontended atomics per tile.
// ---------------------------------------------------------------------------
__global__ __launch_bounds__(256) void k_zpart(
        const __hip_bfloat16* __restrict__ Qb, const __hip_bfloat16* __restrict__ Kb,
        float* __restrict__ Zpart, float* __restrict__ rZ, unsigned* __restrict__ cnt) {
    int l  = threadIdx.x & 63;
    int w  = threadIdx.x >> 6;          // 0..3
    int jt = blockIdx.x >> 4;           // 0..127
    int ic = ((blockIdx.x & 15) << 2) + w;  // 0..63
    int j0 = jt * 64;
    const int ilen = 128;               // 8192 / 64 i-chunks
    int i0 = ic * ilen;
    bf16x8 ka[4];
    #pragma unroll
    for (int f = 0; f < 4; ++f) ka[f] = load_frag8(Kb, j0 + f * 16, l);
    float zac[16];
    #pragma unroll
    for (int t = 0; t < 16; ++t) zac[t] = 0.f;
    const f32x4 z4 = {0.f, 0.f, 0.f, 0.f};
    #pragma unroll 2
    for (int i = i0; i < i0 + ilen; i += 16) {
        bf16x8 qf = load_frag8(Qb, i, l);
        #pragma unroll
        for (int f = 0; f < 4; ++f) {
            f32x4 s = __builtin_amdgcn_mfma_f32_16x16x32_bf16(ka[f], qf, z4, 0, 0, 0);
            #pragma unroll
            for (int r = 0; r < 4; ++r)
                zac[f * 4 + r] += __builtin_amdgcn_exp2f(s[r]);
        }
    }
    #pragma unroll
    for (int t = 0; t < 16; ++t) {
        float z = zac[t];
        z += __shfl_xor(z, 1); z += __shfl_xor(z, 2);
        z += __shfl_xor(z, 4); z += __shfl_xor(z, 8);
        zac[t] = z;
    }
    if ((l & 15) == 0) {
        int jr = (l >> 4) * 4;
        #pragma unroll
        for (int f = 0; f < 4; ++f)
            #pragma unroll
            for (int r = 0; r < 4; ++r)
                Zpart[(size_t)ic * N_TOK + j0 + f * 16 + jr + r] = zac[f * 4 + r];
    }
    // --- last-block reduction of this j-tile ---
    __threadfence();
    __syncthreads();
    __shared__ unsigned oldv;
    __shared__ float zred[64][4];
    if (threadIdx.x == 0) oldv = atomicAdd(&cnt[jt], 1u);
    __syncthreads();
    if (oldv == 15u) {
        __threadfence();                 // acquire: see other blocks' Zpart
        int tj = threadIdx.x & 63, part = threadIdx.x >> 6;
        float zs = 0.f;
        #pragma unroll
        for (int c = 0; c < 16; ++c)
            zs += Zpart[(size_t)(part * 16 + c) * N_TOK + j0 + tj];
        zred[tj][part] = zs;
        __syncthreads();
        if (threadIdx.x < 64) {
            float z = ((zred[threadIdx.x][0] + zred[threadIdx.x][1]) +
                       (zred[threadIdx.x][2] + zred[threadIdx.x][3]));
            rZ[j0 + threadIdx.x] = __builtin_amdgcn_rcpf(z);
        }
    }
}

// ---------------------------------------------------------------------------
// K3 (pass B): oTp[jc][d][i] = sum_{j in chunk jc} (exp2(s~_ij)*rZ_j) v[j][d].
// rZ folded into the P fragment; V unnormalized. exp(S^T) D-frag == B-operand
// layout of mfma_16x16x16_bf16 -> PV needs no shuffles/LDS.
// ---------------------------------------------------------------------------
__global__ __launch_bounds__(256) void k_attn(
        const __hip_bfloat16* __restrict__ Qb, const __hip_bfloat16* __restrict__ Kb,
        const __hip_bfloat16* __restrict__ VTb, const float* __restrict__ rZ,
        __hip_bfloat16* __restrict__ oTp) {
    int l  = threadIdx.x & 63;
    int gw = blockIdx.x * 4 + (threadIdx.x >> 6);
    int it = gw / NCH_O, jc = gw - it * NCH_O;
    int i0 = it * ITILE;
    const int jlen = N_TOK / NCH_O;           // 256
    int j0c = jc * jlen;
    bf16x8 qb[4];
    #pragma unroll
    for (int f = 0; f < 4; ++f) qb[f] = load_frag8(Qb, i0 + f * 16, l);
    f32x4 acc0[4], acc1[4];
    #pragma unroll
    for (int f = 0; f < 4; ++f) { acc0[f] = {0.f,0.f,0.f,0.f}; acc1[f] = {0.f,0.f,0.f,0.f}; }
    const f32x4 z4 = {0.f, 0.f, 0.f, 0.f};
    int lo16 = l & 15, hi4 = (l >> 4) << 2;
    const __hip_bfloat16* v0p = VTb + (size_t)lo16 * N_TOK;
    const __hip_bfloat16* v1p = VTb + (size_t)(lo16 + 16) * N_TOK;
    #pragma unroll 2
    for (int j = j0c; j < j0c + jlen; j += 16) {
        f32x4 rz = *reinterpret_cast<const f32x4*>(rZ + j + hi4);
        bf16x8 kaf = load_frag8(Kb, j, l);
        bf16x4 va0 = *reinterpret_cast<const bf16x4*>(v0p + j + hi4);
        bf16x4 va1 = *reinterpret_cast<const bf16x4*>(v1p + j + hi4);
        #pragma unroll
        for (int f = 0; f < 4; ++f) {
            f32x4 s = __builtin_amdgcn_mfma_f32_16x16x32_bf16(kaf, qb[f], z4, 0, 0, 0);
            bf16x4 e;
            #pragma unroll
            for (int r = 0; r < 4; ++r)
                e[r] = f2bf(__builtin_amdgcn_exp2f(s[r]) * rz[r]);
            acc0[f] = __builtin_amdgcn_mfma_f32_16x16x16bf16_1k(va0, e, acc0[f], 0, 0, 0);
            acc1[f] = __builtin_amdgcn_mfma_f32_16x16x16bf16_1k(va1, e, acc1[f], 0, 0, 0);
        }
    }
    int icol = i0 + lo16;
    #pragma unroll
    for (int f = 0; f < 4; ++f) {
        #pragma unroll
        for (int r = 0; r < 4; ++r) {
            oTp[(size_t)(jc * DH + hi4 + r)      * N_TOK + icol + f * 16] =
                __float2bfloat16(acc0[f][r]);
            oTp[(size_t)(jc * DH + 16 + hi4 + r) * N_TOK + icol + f * 16] =
                __float2bfloat16(acc1[f][r]);
        }
    }
}

// ---------------------------------------------------------------------------
// K4: reduce bf16 oT partials (regs -> LDS tile[32 d][32 n]) then
// y = w4 @ o + b4 + x. Block = 32 tokens; 256 blocks (full chip).
// ---------------------------------------------------------------------------
__global__ __launch_bounds__(256) void k_fin(
        const __hip_bfloat16* __restrict__ oTp, const float* __restrict__ w4,
        const float* __restrict__ b4, const float* __restrict__ x,
        float* __restrict__ y) {
    __shared__ float w4s[64][32];     // [c][d]
    __shared__ float tile[32][36];    // [d][n_local], padded
    int t = threadIdx.x;
    {   // stage w4 (2048 f32, same flat layout)
        const float4* w4v = reinterpret_cast<const float4*>(w4);
        float4* dst = reinterpret_cast<float4*>(&w4s[0][0]);
        dst[t * 2]     = w4v[t * 2];
        dst[t * 2 + 1] = w4v[t * 2 + 1];
    }
    int n0 = blockIdx.x * 32;
    int d = t >> 3, seg = t & 7;      // 4 tokens per seg
    float s[4];
    #pragma unroll
    for (int k = 0; k < 4; ++k) s[k] = 0.f;
    #pragma unroll 4
    for (int c = 0; c < NCH_O; ++c) {
        bf16x4 v = *reinterpret_cast<const bf16x4*>(
            oTp + ((size_t)c * DH + d) * N_TOK + n0 + seg * 4);
        #pragma unroll
        for (int k = 0; k < 4; ++k) s[k] += bf2f(v[k]);
    }
    #pragma unroll
    for (int k = 0; k < 4; ++k) tile[d][seg * 4 + k] = s[k];
    __syncthreads();
    int n_l = t & 31, cg = t >> 5;    // cg 0..7
    int n = n0 + n_l, b = n >> 12, hw = n & 4095;
    #pragma unroll
    for (int ci = 0; ci < 8; ++ci) {
        int c = cg * 8 + ci;
        float acc = b4[c];
        #pragma unroll
        for (int dd = 0; dd < 32; ++dd)
            acc = fmaf(w4s[c][dd], tile[dd][n_l], acc);
        int idx = b * (CCH * HWSZ) + c * HWSZ + hw;
        y[idx] = acc + x[idx];
    }
}

extern "C" void kernel_launch(void* const* d_in, const int* in_sizes, int n_in,
                              void* d_out, int out_size, void* d_ws, size_t ws_size,
                              hipStream_t stream) {
    const float* x  = (const float*)d_in[0];
    const float* w1 = (const float*)d_in[1];
    const float* b1 = (const float*)d_in[2];
    const float* w2 = (const float*)d_in[3];
    const float* b2 = (const float*)d_in[4];
    const float* w3 = (const float*)d_in[5];
    const float* b3 = (const float*)d_in[6];
    const float* w4 = (const float*)d_in[7];
    const float* b4 = (const float*)d_in[8];
    float* y = (float*)d_out;

    char* ws = (char*)d_ws;
    const size_t KB = 1024;
    __hip_bfloat16* Qb  = (__hip_bfloat16*)(ws);                  // 512 KB
    __hip_bfloat16* Kb  = (__hip_bfloat16*)(ws + 512 * KB);       // 512 KB
    __hip_bfloat16* VTb = (__hip_bfloat16*)(ws + 1024 * KB);      // 512 KB
    float*          Zp  = (float*)(ws + 1536 * KB);               // 2 MB
    float*          rZ  = (float*)(ws + 3584 * KB);               // 32 KB
    unsigned*       cnt = (unsigned*)(ws + 3616 * KB);            // 512 B
    __hip_bfloat16* oTp = (__hip_bfloat16*)(ws + 4096 * KB);      // 16 MB

    hipLaunchKernelGGL(k_qkv,   dim3(N_TOK / 8), dim3(256), 0, stream,
                       x, w1, b1, w2, b2, w3, b3, Qb, Kb, VTb, cnt);
    hipLaunchKernelGGL(k_zpart, dim3(2048), dim3(256), 0, stream, Qb, Kb, Zp, rZ, cnt);
    hipLaunchKernelGGL(k_attn,  dim3((N_TOK / ITILE) * NCH_O / 4), dim3(256), 0, stream,
                       Qb, Kb, VTb, rZ, oTp);
    hipLaunchKernelGGL(k_fin,   dim3(N_TOK / 32), dim3(256), 0, stream,
                       oTp, w4, b4, x, y);
}

// Round 6
// 67.422 us; speedup vs baseline: 3.4054x; 3.4054x over previous
//
#include <hip/hip_runtime.h>
#include <hip/hip_bf16.h>

// Problem constants: B=2, C=64, H=64, W=64 -> N=8192 tokens, DH=32.
#define N_TOK   8192
#define DH      32
#define CCH     64
#define HWSZ    4096
#define LOG2E   1.4426950408889634f
#define NCH_Z   32     // i-chunks in pass A (ilen = 256)
#define NCH_O   32     // j-chunks in pass B (jlen = 256)
#define ITILE   64     // i-rows per wave in pass B (4 Q fragments)

typedef __attribute__((ext_vector_type(8))) short  bf16x8;
typedef __attribute__((ext_vector_type(4))) short  bf16x4;
typedef __attribute__((ext_vector_type(4))) float  f32x4;

// Bit-pattern f32 -> bf16 short (for MFMA operand vectors / LDS shorts ONLY —
// never assign the result to a __hip_bfloat16: that would value-convert).
static __device__ __forceinline__ short f2bf(float f) {
    __hip_bfloat16 h = __float2bfloat16(f);
    return __builtin_bit_cast(short, h);
}
static __device__ __forceinline__ float bf2f(short s) {
    unsigned u = ((unsigned)(unsigned short)s) << 16;
    return __builtin_bit_cast(float, u);
}

// A/B fragment for mfma_f32_16x16x32_bf16 from row-major [rows][32] bf16:
// lane l supplies row row0+(l&15), k = 8*(l>>4)..+8 (16B load).
static __device__ __forceinline__ bf16x8 load_frag8(const __hip_bfloat16* __restrict__ base,
                                                    int row0, int l) {
    const __hip_bfloat16* p = base + (size_t)(row0 + (l & 15)) * DH + ((l >> 4) << 3);
    return *reinterpret_cast<const bf16x8*>(p);
}

// ---------------------------------------------------------------------------
// K1: q/k/v projections (1024 blocks, 8 tokens each). Outputs Qb[n][d]
// (pre-scaled by log2e), Kb[n][d], VTb[d][n] (bf16, unnormalized, transposed
// via LDS).
// ---------------------------------------------------------------------------
__global__ __launch_bounds__(256) void k_qkv(
        const float* __restrict__ x,
        const float* __restrict__ w1, const float* __restrict__ b1,
        const float* __restrict__ w2, const float* __restrict__ b2,
        const float* __restrict__ w3, const float* __restrict__ b3,
        __hip_bfloat16* __restrict__ Qb, __hip_bfloat16* __restrict__ Kb,
        __hip_bfloat16* __restrict__ VTb) {
    __shared__ float4 w1s[16][32];
    __shared__ float4 w2s[16][32];
    __shared__ float4 w3s[16][32];
    __shared__ short  vt[32][8];      // [d][n_local]
    int t = threadIdx.x;
    for (int i = t; i < 512; i += 256) {
        int cg = i >> 5, d = i & 31;
        w1s[cg][d] = *reinterpret_cast<const float4*>(w1 + d * CCH + cg * 4);
        w2s[cg][d] = *reinterpret_cast<const float4*>(w2 + d * CCH + cg * 4);
        w3s[cg][d] = *reinterpret_cast<const float4*>(w3 + d * CCH + cg * 4);
    }
    __syncthreads();
    int d = t & 31, nr = t >> 5;
    int n0 = blockIdx.x * 8;
    int n = n0 + nr;
    int b = n >> 12, hw = n & 4095;
    const float* xp = x + (size_t)b * (CCH * HWSZ) + hw;
    float aq = b1[d], ak = b2[d], av = b3[d];
    #pragma unroll
    for (int cg = 0; cg < 16; ++cg) {
        float x0 = xp[(cg * 4 + 0) * HWSZ];
        float x1 = xp[(cg * 4 + 1) * HWSZ];
        float x2 = xp[(cg * 4 + 2) * HWSZ];
        float x3 = xp[(cg * 4 + 3) * HWSZ];
        float4 a = w1s[cg][d];
        aq = fmaf(a.x, x0, aq); aq = fmaf(a.y, x1, aq);
        aq = fmaf(a.z, x2, aq); aq = fmaf(a.w, x3, aq);
        float4 bb = w2s[cg][d];
        ak = fmaf(bb.x, x0, ak); ak = fmaf(bb.y, x1, ak);
        ak = fmaf(bb.z, x2, ak); ak = fmaf(bb.w, x3, ak);
        float4 cc = w3s[cg][d];
        av = fmaf(cc.x, x0, av); av = fmaf(cc.y, x1, av);
        av = fmaf(cc.z, x2, av); av = fmaf(cc.w, x3, av);
    }
    Qb[(size_t)n * DH + d] = __float2bfloat16(aq * LOG2E);
    Kb[(size_t)n * DH + d] = __float2bfloat16(ak);
    vt[d][nr] = f2bf(av);
    __syncthreads();
    if (t < 32) {   // 32 d-rows x 8 tokens, one 16B chunk per row
        bf16x8 row = *reinterpret_cast<const bf16x8*>(&vt[t][0]);
        *reinterpret_cast<bf16x8*>(VTb + (size_t)t * N_TOK + n0) = row;
    }
}

// ---------------------------------------------------------------------------
// K2 (pass A): Zpart[ic][j] = sum_{i in chunk ic} exp2(q~_i . k_j).
// Wave: 64-col j-tile (4 K frags) x one 256-row i-chunk. 4096 waves.
// Plain stores only — no atomics, no fences (R5 lesson: device-scope fences
// cost ~200us on gfx950).
// ---------------------------------------------------------------------------
__global__ __launch_bounds__(256) void k_zpart(
        const __hip_bfloat16* __restrict__ Qb, const __hip_bfloat16* __restrict__ Kb,
        float* __restrict__ Zpart) {
    int l  = threadIdx.x & 63;
    int gw = blockIdx.x * 4 + (threadIdx.x >> 6);
    int jt = gw >> 5;                    // 0..127 (64-col j-tile)
    int ic = gw & 31;                    // 0..31
    int j0 = jt * 64;
    const int ilen = N_TOK / NCH_Z;      // 256
    int i0 = ic * ilen;
    bf16x8 ka[4];
    #pragma unroll
    for (int f = 0; f < 4; ++f) ka[f] = load_frag8(Kb, j0 + f * 16, l);
    float zac[16];
    #pragma unroll
    for (int t = 0; t < 16; ++t) zac[t] = 0.f;
    const f32x4 z4 = {0.f, 0.f, 0.f, 0.f};
    #pragma unroll 2
    for (int i = i0; i < i0 + ilen; i += 16) {
        bf16x8 qf = load_frag8(Qb, i, l);
        #pragma unroll
        for (int f = 0; f < 4; ++f) {
            f32x4 s = __builtin_amdgcn_mfma_f32_16x16x32_bf16(ka[f], qf, z4, 0, 0, 0);
            #pragma unroll
            for (int r = 0; r < 4; ++r)
                zac[f * 4 + r] += __builtin_amdgcn_exp2f(s[r]);
        }
    }
    #pragma unroll
    for (int t = 0; t < 16; ++t) {
        float z = zac[t];
        z += __shfl_xor(z, 1); z += __shfl_xor(z, 2);
        z += __shfl_xor(z, 4); z += __shfl_xor(z, 8);
        zac[t] = z;
    }
    if ((l & 15) == 0) {
        int jr = (l >> 4) * 4;
        #pragma unroll
        for (int f = 0; f < 4; ++f)
            #pragma unroll
            for (int r = 0; r < 4; ++r)
                Zpart[(size_t)ic * N_TOK + j0 + f * 16 + jr + r] = zac[f * 4 + r];
    }
}

// ---------------------------------------------------------------------------
// K3 (pass B): block = one 256-col j-chunk (shared by its 4 waves) x four
// 64-row i-tiles. Preamble: block reduces Zpart over the 32 i-chunks for its
// 256 columns (fixed order -> deterministic) into LDS rzs[] = rcp(Z).
// Main loop: oTp[jc][d][i] = sum_j (exp2(s~_ij)*rZ_j) v[j][d]; exp(S^T)
// D-frag == B-operand layout of mfma_16x16x16_bf16 (no shuffles/LDS for P).
// ---------------------------------------------------------------------------
__global__ __launch_bounds__(256) void k_attn(
        const __hip_bfloat16* __restrict__ Qb, const __hip_bfloat16* __restrict__ Kb,
        const __hip_bfloat16* __restrict__ VTb, const float* __restrict__ Zpart,
        __hip_bfloat16* __restrict__ oTp) {
    __shared__ float rzs[256];
    int t = threadIdx.x;
    int jc  = blockIdx.x & 31;           // j-chunk (shared by block)
    int itg = blockIdx.x >> 5;           // 0..31 i-tile group
    const int jlen = N_TOK / NCH_O;      // 256
    int j0c = jc * jlen;
    {   // Z reduction for this j-chunk: 256 threads, one column each
        float z = 0.f;
        #pragma unroll 8
        for (int c = 0; c < NCH_Z; ++c) z += Zpart[(size_t)c * N_TOK + j0c + t];
        rzs[t] = __builtin_amdgcn_rcpf(z);
    }
    __syncthreads();
    int l = t & 63;
    int it = itg * 4 + (t >> 6);
    int i0 = it * ITILE;
    bf16x8 qb[4];
    #pragma unroll
    for (int f = 0; f < 4; ++f) qb[f] = load_frag8(Qb, i0 + f * 16, l);
    f32x4 acc0[4], acc1[4];
    #pragma unroll
    for (int f = 0; f < 4; ++f) { acc0[f] = {0.f,0.f,0.f,0.f}; acc1[f] = {0.f,0.f,0.f,0.f}; }
    const f32x4 z4 = {0.f, 0.f, 0.f, 0.f};
    int lo16 = l & 15, hi4 = (l >> 4) << 2;
    const __hip_bfloat16* v0p = VTb + (size_t)lo16 * N_TOK;
    const __hip_bfloat16* v1p = VTb + (size_t)(lo16 + 16) * N_TOK;
    #pragma unroll 2
    for (int jl = 0; jl < jlen; jl += 16) {
        int j = j0c + jl;
        f32x4 rz = *reinterpret_cast<const f32x4*>(&rzs[jl + hi4]);
        bf16x8 kaf = load_frag8(Kb, j, l);
        bf16x4 va0 = *reinterpret_cast<const bf16x4*>(v0p + j + hi4);
        bf16x4 va1 = *reinterpret_cast<const bf16x4*>(v1p + j + hi4);
        #pragma unroll
        for (int f = 0; f < 4; ++f) {
            f32x4 s = __builtin_amdgcn_mfma_f32_16x16x32_bf16(kaf, qb[f], z4, 0, 0, 0);
            bf16x4 e;
            #pragma unroll
            for (int r = 0; r < 4; ++r)
                e[r] = f2bf(__builtin_amdgcn_exp2f(s[r]) * rz[r]);
            acc0[f] = __builtin_amdgcn_mfma_f32_16x16x16bf16_1k(va0, e, acc0[f], 0, 0, 0);
            acc1[f] = __builtin_amdgcn_mfma_f32_16x16x16bf16_1k(va1, e, acc1[f], 0, 0, 0);
        }
    }
    int icol = i0 + lo16;
    #pragma unroll
    for (int f = 0; f < 4; ++f) {
        #pragma unroll
        for (int r = 0; r < 4; ++r) {
            oTp[(size_t)(jc * DH + hi4 + r)      * N_TOK + icol + f * 16] =
                __float2bfloat16(acc0[f][r]);
            oTp[(size_t)(jc * DH + 16 + hi4 + r) * N_TOK + icol + f * 16] =
                __float2bfloat16(acc1[f][r]);
        }
    }
}

// ---------------------------------------------------------------------------
// K4: reduce bf16 oT partials (regs -> LDS tile[32 d][32 n]) then
// y = w4 @ o + b4 + x. Block = 32 tokens; 256 blocks (full chip).
// ---------------------------------------------------------------------------
__global__ __launch_bounds__(256) void k_fin(
        const __hip_bfloat16* __restrict__ oTp, const float* __restrict__ w4,
        const float* __restrict__ b4, const float* __restrict__ x,
        float* __restrict__ y) {
    __shared__ float w4s[64][32];     // [c][d]
    __shared__ float tile[32][36];    // [d][n_local], padded
    int t = threadIdx.x;
    {   // stage w4 (2048 f32, same flat layout)
        const float4* w4v = reinterpret_cast<const float4*>(w4);
        float4* dst = reinterpret_cast<float4*>(&w4s[0][0]);
        dst[t * 2]     = w4v[t * 2];
        dst[t * 2 + 1] = w4v[t * 2 + 1];
    }
    int n0 = blockIdx.x * 32;
    int d = t >> 3, seg = t & 7;      // 4 tokens per seg
    float s[4];
    #pragma unroll
    for (int k = 0; k < 4; ++k) s[k] = 0.f;
    #pragma unroll 4
    for (int c = 0; c < NCH_O; ++c) {
        bf16x4 v = *reinterpret_cast<const bf16x4*>(
            oTp + ((size_t)c * DH + d) * N_TOK + n0 + seg * 4);
        #pragma unroll
        for (int k = 0; k < 4; ++k) s[k] += bf2f(v[k]);
    }
    #pragma unroll
    for (int k = 0; k < 4; ++k) tile[d][seg * 4 + k] = s[k];
    __syncthreads();
    int n_l = t & 31, cg = t >> 5;    // cg 0..7
    int n = n0 + n_l, b = n >> 12, hw = n & 4095;
    #pragma unroll
    for (int ci = 0; ci < 8; ++ci) {
        int c = cg * 8 + ci;
        float acc = b4[c];
        #pragma unroll
        for (int dd = 0; dd < 32; ++dd)
            acc = fmaf(w4s[c][dd], tile[dd][n_l], acc);
        int idx = b * (CCH * HWSZ) + c * HWSZ + hw;
        y[idx] = acc + x[idx];
    }
}

extern "C" void kernel_launch(void* const* d_in, const int* in_sizes, int n_in,
                              void* d_out, int out_size, void* d_ws, size_t ws_size,
                              hipStream_t stream) {
    const float* x  = (const float*)d_in[0];
    const float* w1 = (const float*)d_in[1];
    const float* b1 = (const float*)d_in[2];
    const float* w2 = (const float*)d_in[3];
    const float* b2 = (const float*)d_in[4];
    const float* w3 = (const float*)d_in[5];
    const float* b3 = (const float*)d_in[6];
    const float* w4 = (const float*)d_in[7];
    const float* b4 = (const float*)d_in[8];
    float* y = (float*)d_out;

    char* ws = (char*)d_ws;
    const size_t KB = 1024;
    __hip_bfloat16* Qb  = (__hip_bfloat16*)(ws);                  // 512 KB
    __hip_bfloat16* Kb  = (__hip_bfloat16*)(ws + 512 * KB);       // 512 KB
    __hip_bfloat16* VTb = (__hip_bfloat16*)(ws + 1024 * KB);      // 512 KB
    float*          Zp  = (float*)(ws + 1536 * KB);               // 1 MB (32 x 8192 f32)
    __hip_bfloat16* oTp = (__hip_bfloat16*)(ws + 2560 * KB);      // 16 MB

    hipLaunchKernelGGL(k_qkv,   dim3(N_TOK / 8), dim3(256), 0, stream,
                       x, w1, b1, w2, b2, w3, b3, Qb, Kb, VTb);
    hipLaunchKernelGGL(k_zpart, dim3(1024), dim3(256), 0, stream, Qb, Kb, Zp);
    hipLaunchKernelGGL(k_attn,  dim3(1024), dim3(256), 0, stream,
                       Qb, Kb, VTb, Zp, oTp);
    hipLaunchKernelGGL(k_fin,   dim3(N_TOK / 32), dim3(256), 0, stream,
                       oTp, w4, b4, x, y);
}